// Round 9
// baseline (657.827 us; speedup 1.0000x reference)
//
#include <hip/hip_runtime.h>
#include <hip/hip_bf16.h>

#define B_ 128
#define E_ 512
#define H_ 1024
#define S_ 514
#define NEGV -1000000.0f

typedef __attribute__((ext_vector_type(8))) short bf16x8;
typedef __attribute__((ext_vector_type(4))) short s16x4;
typedef __attribute__((ext_vector_type(4))) float f32x4;

typedef __attribute__((address_space(1))) const void* gptr_t;
typedef __attribute__((address_space(3))) void* lptr_t;

__device__ __forceinline__ short f2bf(float f) {
  unsigned u = __builtin_bit_cast(unsigned, f);
  return (short)((u + 0x8000u) >> 16);
}

__device__ __forceinline__ float gelu_f(float x) {
  return 0.5f * x * (1.0f + erff(x * 0.7071067811865475f));
}

// ---------------- init: Q1 rows = b1 (broadcast), N1 = A1 = 0
__global__ void init_q1(const float* __restrict__ b1, float* __restrict__ Q1,
                        float* __restrict__ N1, float* __restrict__ A1) {
  int b = blockIdx.x;          // 0..129
  int t = threadIdx.x;         // 0..255, 4 floats each
  if (b < B_) {
    f32x4 v = *(const f32x4*)(b1 + t * 4);
    *(f32x4*)(Q1 + (size_t)b * H_ + t * 4) = v;
  } else if (b == B_) {
    *(f32x4*)(N1 + t * 4) = (f32x4){0.f, 0.f, 0.f, 0.f};
  } else {
    *(f32x4*)(A1 + t * 4) = (f32x4){0.f, 0.f, 0.f, 0.f};
  }
}

// ---------------- prep2: Q1 += query @ W1q ; N1 += null @ W1k ; A1 += new @ W1k
#define RPB 8
__global__ void prep2(const float* __restrict__ query, const float* __restrict__ W1,
                      const float* __restrict__ nulla, const float* __restrict__ newa,
                      float* __restrict__ Q1, float* __restrict__ N1, float* __restrict__ A1) {
  int bid = blockIdx.x;        // 17 rowGroups * 16 dchunks = 272
  int rg = bid >> 4;           // 0..16 (16 = special group: null,new)
  int dc = bid & 15;           // 64 d's each
  int t = threadIdx.x;
  bool special = (rg == 16);
  int woff = special ? H_ : 0;

  __shared__ float vec[RPB][64];
  {
    int r = t >> 6, dd = t & 63;
    #pragma unroll
    for (int rr = 0; rr < 2; ++rr) {
      int row = r + rr * 4;
      float v = 0.f;
      if (!special) v = query[(size_t)(rg * RPB + row) * H_ + dc * 64 + dd];
      else if (row == 0) v = nulla[dc * 64 + dd];
      else if (row == 1) v = newa[dc * 64 + dd];
      vec[row][dd] = v;
    }
  }
  __syncthreads();

  const float* wp = W1 + (size_t)(woff + dc * 64) * H_ + t * 4;
  f32x4 acc[RPB];
  #pragma unroll
  for (int r = 0; r < RPB; ++r) acc[r] = (f32x4){0.f, 0.f, 0.f, 0.f};

  #pragma unroll 4
  for (int dd = 0; dd < 64; ++dd) {
    f32x4 w = *(const f32x4*)(wp + (size_t)dd * H_);
    #pragma unroll
    for (int r = 0; r < RPB; ++r) {
      float v = vec[r][dd];
      acc[r][0] += v * w[0]; acc[r][1] += v * w[1];
      acc[r][2] += v * w[2]; acc[r][3] += v * w[3];
    }
  }

  if (!special) {
    #pragma unroll
    for (int r = 0; r < RPB; ++r) {
      float* dst = Q1 + (size_t)(rg * RPB + r) * H_ + t * 4;
      atomicAdd(dst + 0, acc[r][0]); atomicAdd(dst + 1, acc[r][1]);
      atomicAdd(dst + 2, acc[r][2]); atomicAdd(dst + 3, acc[r][3]);
    }
  } else {
    float* d0 = N1 + t * 4;
    atomicAdd(d0 + 0, acc[0][0]); atomicAdd(d0 + 1, acc[0][1]);
    atomicAdd(d0 + 2, acc[0][2]); atomicAdd(d0 + 3, acc[0][3]);
    float* d1 = A1 + t * 4;
    atomicAdd(d1 + 0, acc[1][0]); atomicAdd(d1 + 1, acc[1][1]);
    atomicAdd(d1 + 2, acc[1][2]); atomicAdd(d1 + 3, acc[1][3]);
  }
}

// ---------------- prep: w1kT[n][k] = bf16(W1[H+k][n])
__global__ void transpose_w1k(const float* __restrict__ W1, short* __restrict__ w1kT) {
  __shared__ float tb[64][65];
  int k0 = (blockIdx.x & 15) * 64;
  int n0 = (blockIdx.x >> 4) * 64;
  int x = threadIdx.x & 63;
  int ty = threadIdx.x >> 6;  // 0..3
  #pragma unroll
  for (int i = 0; i < 16; ++i) {
    int row = i * 4 + ty;  // k_local
    tb[row][x] = W1[(size_t)(H_ + k0 + row) * H_ + n0 + x];
  }
  __syncthreads();
  #pragma unroll
  for (int i = 0; i < 16; ++i) {
    int row = i * 4 + ty;  // n_local
    w1kT[(size_t)(n0 + row) * H_ + k0 + x] = f2bf(tb[x][row]);
  }
}

// ---------------- base scores: b2 +/- mention + mask, plus full null/new slots
__global__ void finalize_base(const int* __restrict__ es, const float* __restrict__ mention,
                              const float* __restrict__ W2, const float* __restrict__ b2,
                              const float* __restrict__ Q1, const float* __restrict__ N1,
                              const float* __restrict__ A1, float* __restrict__ scores) {
  int b = blockIdx.x;
  int t = threadIdx.x;
  float b2v = b2[0], mv = mention[b];
  int esz = es[b];
  for (int s = t; s < S_; s += 256) {
    float base = b2v + (s == 0 ? -mv : mv);
    if (s >= esz + 1 && s <= E_) base += NEGV;
    scores[b * S_ + s] = base;
  }
  float sum0 = 0.f, sum1 = 0.f;
  for (int h = t; h < H_; h += 256) {
    float q = Q1[b * H_ + h], w = W2[h];
    sum0 += gelu_f(q + N1[h]) * w;
    sum1 += gelu_f(q + A1[h]) * w;
  }
  #pragma unroll
  for (int m = 32; m > 0; m >>= 1) { sum0 += __shfl_xor(sum0, m); sum1 += __shfl_xor(sum1, m); }
  __shared__ float red0[4], red1[4];
  int lanei = t & 63, wdi = t >> 6;
  if (lanei == 0) { red0[wdi] = sum0; red1[wdi] = sum1; }
  __syncthreads();
  if (t == 0) {
    scores[b * S_ + 0]      += red0[0] + red0[1] + red0[2] + red0[3];
    scores[b * S_ + S_ - 1] += red1[0] + red1[1] + red1[2] + red1[3];
  }
}

// ================ GEMM: fused cvt A-path + B double-buffer pipeline
// Iteration t: [S1: drains B(t) gloads (issued last iter, covered by MFMA phase)
//               + A(t) reg loads; everyone done reading As]
//              cvt+write A(t) -> As (b128, swizzled)
//              [S2: drains only the fast A ds_writes]
//              issue B(t+1) -> Bs[nx]; load A(t+1) -> aReg   (fly during MFMA)
//              MFMA(As, Bs[cur])
#define GBM 128
#define GBN 128
#define GBK 64

__global__ __launch_bounds__(256, 3) void gemm_fused(
    const float* __restrict__ keys, const short* __restrict__ Bm,
    const float* __restrict__ Q1, const float* __restrict__ W2,
    float* __restrict__ scores) {
  __shared__ short As[GBM * GBK];      // 16 KB, swizzled content
  __shared__ short Bs[2][GBN * GBK];   // 2 x 16 KB, linear dest (read with XOR)

  int bid = blockIdx.x;
  int cpx = gridDim.x >> 3;   // 4096/8 = 512, bijective XCD swizzle
  bid = (bid & 7) * cpx + (bid >> 3);
  int tileM = bid >> 3;
  int tileN = bid & 7;
  int row0 = tileM * GBM;
  int col0 = tileN * GBN;

  int t = threadIdx.x;
  int lane = t & 63;
  int wid = t >> 6;
  int wr = wid >> 1, wc = wid & 1;
  int l15 = lane & 15, lHi = lane >> 4;

  // ---- A staging: thread t -> 16B-unit uc = t&7, rows rBase + p*32 (p=0..3)
  int uc = t & 7;
  int rBase = t >> 3;          // 0..31
  const float* aBase = keys + (size_t)(row0 + rBase) * H_ + uc * 8;
  // unit involution: phys_unit = uc ^ (row & 7); (rBase+p*32)&7 == rBase&7
  char* aWr = (char*)As + rBase * 128 + ((uc ^ (rBase & 7)) << 4);

  // ---- B staging (global_load_lds): round-5-validated path, alternating dest
  int srcRow = lane >> 3;
  int srcColE = ((lane & 7) ^ (lane >> 3)) << 3;
  const short* bSrc = Bm + (size_t)(col0 + wid * 32 + srcRow) * H_ + srcColE;
  int bDstOff = (wid * 4) * 512;

  f32x4 aReg[4][2];
  f32x4 acc[4][4];
  #pragma unroll
  for (int m = 0; m < 4; ++m)
    #pragma unroll
    for (int n = 0; n < 4; ++n) acc[m][n] = (f32x4){0.f, 0.f, 0.f, 0.f};

  // prologue: A(0) regs + B(0) -> Bs[0]
  #pragma unroll
  for (int p = 0; p < 4; ++p) {
    aReg[p][0] = *(const f32x4*)(aBase + (size_t)p * 32 * H_);
    aReg[p][1] = *(const f32x4*)(aBase + (size_t)p * 32 * H_ + 4);
  }
  #pragma unroll
  for (int i = 0; i < 4; ++i)
    __builtin_amdgcn_global_load_lds((gptr_t)(bSrc + (size_t)i * 8 * H_),
                                     (lptr_t)(&Bs[0][bDstOff + i * 512]), 16, 0, 0);

  int swz = (l15 & 7) << 4;
  const char* aRd = (const char*)As + (wr * 64 + l15) * 128;
  const char* bRd0 = (const char*)&Bs[0][0] + (wc * 64 + l15) * 128;
  const char* bRd1 = (const char*)&Bs[1][0] + (wc * 64 + l15) * 128;

  for (int ti = 0; ti < H_ / GBK; ++ti) {
    int cur = ti & 1;
    __syncthreads();   // S1: drains B(ti) + A(ti) reg loads; As free to overwrite
    // A(ti): cvt + swizzled b128 writes
    #pragma unroll
    for (int p = 0; p < 4; ++p) {
      bf16x8 v;
      #pragma unroll
      for (int j = 0; j < 4; ++j) { v[j] = f2bf(aReg[p][0][j]); v[4 + j] = f2bf(aReg[p][1][j]); }
      *(bf16x8*)(aWr + p * 4096) = v;   // 32 rows * 128B = 4096B stride
    }
    __syncthreads();   // S2: only the A ds_writes to drain (fast)
    int k1 = (ti + 1) * GBK;
    if (k1 < H_) {     // stage next tile during the MFMA phase
      short* bDstN = (cur ? &Bs[0][0] : &Bs[1][0]) + bDstOff;
      #pragma unroll
      for (int i = 0; i < 4; ++i)
        __builtin_amdgcn_global_load_lds((gptr_t)(bSrc + (size_t)i * 8 * H_ + k1),
                                         (lptr_t)(bDstN + i * 512), 16, 0, 0);
      #pragma unroll
      for (int p = 0; p < 4; ++p) {
        aReg[p][0] = *(const f32x4*)(aBase + (size_t)p * 32 * H_ + k1);
        aReg[p][1] = *(const f32x4*)(aBase + (size_t)p * 32 * H_ + k1 + 4);
      }
    }
    const char* bRdCur = cur ? bRd1 : bRd0;
    #pragma unroll
    for (int kk = 0; kk < 2; ++kk) {
      bf16x8 af[4], bv[4];
      #pragma unroll
      for (int m = 0; m < 4; ++m)
        af[m] = *(const bf16x8*)(aRd + m * 2048 + (((kk << 6) | (lHi << 4)) ^ swz));
      #pragma unroll
      for (int n = 0; n < 4; ++n)
        bv[n] = *(const bf16x8*)(bRdCur + n * 2048 + (((kk << 6) | (lHi << 4)) ^ swz));
      #pragma unroll
      for (int m = 0; m < 4; ++m)
        #pragma unroll
        for (int n = 0; n < 4; ++n)
          acc[m][n] = __builtin_amdgcn_mfma_f32_16x16x32_bf16(af[m], bv[n], acc[m][n], 0, 0, 0);
    }
  }

  // epilogue: pre = acc + Q1[b,col]; score_part[row] = sum_col gelu(pre)*W2[col]
  int bIdx = row0 >> 9;
  float q1v[4], w2v[4];
  #pragma unroll
  for (int n = 0; n < 4; ++n) {
    int col = col0 + wc * 64 + n * 16 + l15;
    q1v[n] = Q1[bIdx * H_ + col];
    w2v[n] = W2[col];
  }
  #pragma unroll
  for (int m = 0; m < 4; ++m) {
    float part[4] = {0.f, 0.f, 0.f, 0.f};
    #pragma unroll
    for (int n = 0; n < 4; ++n)
      #pragma unroll
      for (int i = 0; i < 4; ++i)
        part[i] += gelu_f(acc[m][n][i] + q1v[n]) * w2v[n];
    #pragma unroll
    for (int i = 0; i < 4; ++i) {
      float v = part[i];
      v += __shfl_xor(v, 1);
      v += __shfl_xor(v, 2);
      v += __shfl_xor(v, 4);
      v += __shfl_xor(v, 8);
      if (l15 == 0) {
        int row = row0 + wr * 64 + m * 16 + lHi * 4 + i;
        int s = (row & 511) + 1;
        atomicAdd(&scores[bIdx * S_ + s], v);
      }
    }
  }
}

extern "C" void kernel_launch(void* const* d_in, const int* in_sizes, int n_in,
                              void* d_out, int out_size, void* d_ws, size_t ws_size,
                              hipStream_t stream) {
  const float* query   = (const float*)d_in[0];
  const float* keys    = (const float*)d_in[1];
  const int*   esz     = (const int*)d_in[2];
  const float* mention = (const float*)d_in[3];
  const float* W1      = (const float*)d_in[4];
  const float* b1      = (const float*)d_in[5];
  const float* W2      = (const float*)d_in[6];
  const float* b2      = (const float*)d_in[7];
  const float* nulla   = (const float*)d_in[8];
  const float* newa    = (const float*)d_in[9];
  float* scores = (float*)d_out;

  const size_t w1kTBytes = (size_t)H_ * H_ * 2;   // 2 MB
  short* w1kT = (short*)d_ws;
  float* Q1   = (float*)((char*)d_ws + w1kTBytes);
  float* N1   = Q1 + (size_t)B_ * H_;
  float* A1   = N1 + H_;

  init_q1<<<130, 256, 0, stream>>>(b1, Q1, N1, A1);
  prep2<<<272, 256, 0, stream>>>(query, W1, nulla, newa, Q1, N1, A1);
  transpose_w1k<<<256, 256, 0, stream>>>(W1, w1kT);
  finalize_base<<<B_, 256, 0, stream>>>(esz, mention, W2, b2, Q1, N1, A1, scores);
  gemm_fused<<<4096, 256, 0, stream>>>(keys, w1kT, Q1, W2, scores);
}